// Round 3
// baseline (1346.071 us; speedup 1.0000x reference)
//
#include <hip/hip_runtime.h>
#include <hip/hip_bf16.h>

#define N_NODES 20000
#define NH      8
#define GSZ     625     // nodes per pass-2 group (32 groups * 625 = 20000)
#define NTILES  10      // ceil(625/64)
#define FEPS    1e-6f

typedef __attribute__((ext_vector_type(8))) short bf16x8;
typedef __attribute__((ext_vector_type(4))) float f32x4;
typedef unsigned short u16;

__device__ __forceinline__ float bf2f(u16 u) {
    union { unsigned int i; float f; } v; v.i = ((unsigned int)u) << 16; return v.f;
}
__device__ __forceinline__ u16 f2bf(float f) {
    union { float f; unsigned int i; } v; v.f = f;
    return (u16)((v.i + 0x7fffu + ((v.i >> 16) & 1u)) >> 16);
}
__device__ __forceinline__ int pk2(float a, float b) {
    return (int)f2bf(a) | ((int)f2bf(b) << 16);
}
// convert 8 consecutive fp32 -> 8 bf16 packed in int4
__device__ __forceinline__ int4 cvt8(const float* __restrict__ s) {
    float4 a = *(const float4*)s;
    float4 b = *(const float4*)(s + 4);
    int4 w;
    w.x = pk2(a.x, a.y); w.y = pk2(a.z, a.w);
    w.z = pk2(b.x, b.y); w.w = pk2(b.z, b.w);
    return w;
}

// ---------------- fp32 -> bf16 convert (vectorized x4) ----------------
__global__ void f2bf4_kernel(const float* __restrict__ src, u16* __restrict__ dst, int n4) {
    int i = blockIdx.x * blockDim.x + threadIdx.x;
    if (i >= n4) return;
    float4 v = reinterpret_cast<const float4*>(src)[i];
    ushort4 o;
    o.x = f2bf(v.x); o.y = f2bf(v.y); o.z = f2bf(v.z); o.w = f2bf(v.w);
    reinterpret_cast<ushort4*>(dst)[i] = o;
}

// ---------------- Wavg[o][d] = (1/8) sum_h sum_e vmap[o,e] * Wv[h,e,d]  (bf16 out) ----------------
__global__ __launch_bounds__(256) void wavg_kernel(const float* __restrict__ Wv,
                                                   const float* __restrict__ vmap_w,
                                                   u16* __restrict__ Wavg)
{
    const int o0 = blockIdx.x * 4, t = threadIdx.x;
    __shared__ float vml[4 * 256];
#pragma unroll
    for (int p = 0; p < 4; ++p) {
        int idx = p * 256 + t;
        int row = idx >> 8, col = idx & 255;
        vml[idx] = vmap_w[(size_t)(o0 + row) * 256 + col];
    }
    __syncthreads();
    const int d = t;
    float a0 = 0.f, a1 = 0.f, a2 = 0.f, a3 = 0.f;
    for (int h = 0; h < NH; ++h) {
        const float* Wh = Wv + (size_t)h * 65536;
        for (int e = 0; e < 256; ++e) {
            float w = Wh[(size_t)e * 256 + d];
            a0 += vml[e] * w;
            a1 += vml[256 + e] * w;
            a2 += vml[512 + e] * w;
            a3 += vml[768 + e] * w;
        }
    }
    Wavg[(size_t)(o0 + 0) * 256 + d] = f2bf(a0 * 0.125f);
    Wavg[(size_t)(o0 + 1) * 256 + d] = f2bf(a1 * 0.125f);
    Wavg[(size_t)(o0 + 2) * 256 + d] = f2bf(a2 * 0.125f);
    Wavg[(size_t)(o0 + 3) * 256 + d] = f2bf(a3 * 0.125f);
}

// ---------------- bavg[o] = vmap_b[o] + sum_e vmap[o,e] * (1/8 sum_h bv[h,e]) ----------------
__global__ __launch_bounds__(256) void bavg_kernel(const float* __restrict__ vmap_w,
                                                   const float* __restrict__ bv,
                                                   const float* __restrict__ vmap_b,
                                                   float* __restrict__ bavg)
{
    __shared__ float bva[256];
    const int t = threadIdx.x;
    float s = 0.f;
    for (int h = 0; h < NH; ++h) s += bv[h * 256 + t];
    bva[t] = s * 0.125f;
    __syncthreads();
    float acc = vmap_b[t];
    for (int e = 0; e < 256; ++e) acc += vmap_w[(size_t)t * 256 + e] * bva[e];
    bavg[t] = acc;
}

// ---------------- pass 2: fused K/V proj + phi + ktv/ksum accumulation ----------------
// grid (32 groups, 8 heads); ktvT[h][d][m] += sum_n phi_k[n,m]*v[n,d]
__global__ __launch_bounds__(256, 1) void pass2_kernel(
    const float* __restrict__ src, const float* __restrict__ Wk, const float* __restrict__ bk,
    const float* __restrict__ Wv, const float* __restrict__ bv, const float* __restrict__ ns_ptr,
    float* __restrict__ ktvT, float* __restrict__ ksum)
{
    const int g = blockIdx.x, h = blockIdx.y;
    const int t = threadIdx.x;
    const int lane = t & 63, wid = t >> 6;
    const int r16 = lane & 15, kgrp = lane >> 4;

    __shared__ u16 Xs[64 * 256];   // [n][d]
    __shared__ u16 Ws[256 * 64];   // [m][d-chunk]
    __shared__ u16 KT[256 * 64];   // [m][n]  (k', then phi)
    __shared__ u16 VT[256 * 64];   // [d][n]
    __shared__ float red[512];
    __shared__ float scl[64];

    const float inv_ns = 1.0f / fabsf(ns_ptr[0]);
    const float* Wkh = Wk + (size_t)h * 65536;
    const float* Wvh = Wv + (size_t)h * 65536;

    f32x4 kacc[4][16];
#pragma unroll
    for (int i = 0; i < 4; ++i)
#pragma unroll
        for (int j = 0; j < 16; ++j) kacc[i][j] = (f32x4){0.f, 0.f, 0.f, 0.f};
    float ksr = 0.f;

    for (int it = 0; it < NTILES; ++it) {
        const int ln0 = it * 64;
        // ---- stage X tile (fp32 -> bf16, zero-fill invalid rows) ----
#pragma unroll
        for (int p = 0; p < 8; ++p) {
            int id = p * 256 + t;
            int row = id >> 5, col = (id & 31) * 8;
            int4 w = {0, 0, 0, 0};
            if (ln0 + row < GSZ)
                w = cvt8(src + ((size_t)(g * GSZ + ln0 + row) * 256 + col));
            *(int4*)&Xs[row * 256 + col] = w;
        }
        __syncthreads();

        f32x4 acc2[4][4];
        // ---- K-GEMM: C[m 256][n 64], contraction over d ----
#pragma unroll
        for (int i = 0; i < 4; ++i)
#pragma unroll
            for (int j = 0; j < 4; ++j) acc2[i][j] = (f32x4){0.f, 0.f, 0.f, 0.f};
        for (int kc = 0; kc < 4; ++kc) {
#pragma unroll
            for (int p = 0; p < 8; ++p) {
                int id = p * 256 + t;
                int m = id >> 3, dc = (id & 7) * 8;
                *(int4*)&Ws[m * 64 + dc] = cvt8(Wkh + ((size_t)m * 256 + kc * 64 + dc));
            }
            __syncthreads();
#pragma unroll
            for (int kk = 0; kk < 2; ++kk) {
                bf16x8 a[4];
#pragma unroll
                for (int i = 0; i < 4; ++i)
                    a[i] = *(const bf16x8*)&Ws[(wid * 64 + i * 16 + r16) * 64 + kk * 32 + kgrp * 8];
#pragma unroll
                for (int j = 0; j < 4; ++j) {
                    bf16x8 b = *(const bf16x8*)&Xs[(j * 16 + r16) * 256 + kc * 64 + kk * 32 + kgrp * 8];
#pragma unroll
                    for (int i = 0; i < 4; ++i)
                        acc2[i][j] = __builtin_amdgcn_mfma_f32_16x16x32_bf16(a[i], b, acc2[i][j], 0, 0, 0);
                }
            }
            __syncthreads();
        }
        // epilogue -> KT (relu + eps) * inv_ns
#pragma unroll
        for (int i = 0; i < 4; ++i) {
#pragma unroll
            for (int j = 0; j < 4; ++j) {
                int n = j * 16 + r16;
#pragma unroll
                for (int r = 0; r < 4; ++r) {
                    int m = wid * 64 + i * 16 + kgrp * 4 + r;
                    float x = acc2[i][j][r] + bk[h * 256 + m];
                    x = (fmaxf(x, 0.f) + FEPS) * inv_ns;
                    KT[m * 64 + n] = f2bf(x);
                }
            }
        }
        __syncthreads();
        // ---- column reductions: s1 = sum_m k'^2, s2 = sum_m k'^4 per node ----
        {
            int c = t & 63, ch = t >> 6;
            float s1 = 0.f, s2 = 0.f;
#pragma unroll
            for (int i = 0; i < 64; ++i) {
                float x = bf2f(KT[(ch * 64 + i) * 64 + c]);
                float q = x * x;
                s1 += q; s2 += q * q;
            }
            red[ch * 64 + c] = s1;
            red[256 + ch * 64 + c] = s2;
        }
        __syncthreads();
        if (t < 64) {
            float s1 = red[t] + red[64 + t] + red[128 + t] + red[192 + t];
            float s2 = red[256 + t] + red[320 + t] + red[384 + t] + red[448 + t];
            scl[t] = (ln0 + t < GSZ) ? sqrtf(s1) / sqrtf(s2) : 0.f;
        }
        __syncthreads();
        // ---- phi in place (row m = t) + ksum accumulation ----
        {
            const int m = t;
            float kp = 0.f;
#pragma unroll
            for (int j = 0; j < 8; ++j) {
                bf16x8 v8 = *(const bf16x8*)&KT[m * 64 + j * 8];
                bf16x8 w8;
#pragma unroll
                for (int jj = 0; jj < 8; ++jj) {
                    float x = bf2f((u16)v8[jj]);
                    float ph = x * x * scl[j * 8 + jj];
                    u16 pb = f2bf(ph);
                    w8[jj] = (short)pb;
                    kp += bf2f(pb);
                }
                *(bf16x8*)&KT[m * 64 + j * 8] = w8;
            }
            ksr += kp;
        }
        // ---- V-GEMM: C[d 256][n 64] ----
#pragma unroll
        for (int i = 0; i < 4; ++i)
#pragma unroll
            for (int j = 0; j < 4; ++j) acc2[i][j] = (f32x4){0.f, 0.f, 0.f, 0.f};
        for (int kc = 0; kc < 4; ++kc) {
#pragma unroll
            for (int p = 0; p < 8; ++p) {
                int id = p * 256 + t;
                int m = id >> 3, dc = (id & 7) * 8;
                *(int4*)&Ws[m * 64 + dc] = cvt8(Wvh + ((size_t)m * 256 + kc * 64 + dc));
            }
            __syncthreads();
#pragma unroll
            for (int kk = 0; kk < 2; ++kk) {
                bf16x8 a[4];
#pragma unroll
                for (int i = 0; i < 4; ++i)
                    a[i] = *(const bf16x8*)&Ws[(wid * 64 + i * 16 + r16) * 64 + kk * 32 + kgrp * 8];
#pragma unroll
                for (int j = 0; j < 4; ++j) {
                    bf16x8 b = *(const bf16x8*)&Xs[(j * 16 + r16) * 256 + kc * 64 + kk * 32 + kgrp * 8];
#pragma unroll
                    for (int i = 0; i < 4; ++i)
                        acc2[i][j] = __builtin_amdgcn_mfma_f32_16x16x32_bf16(a[i], b, acc2[i][j], 0, 0, 0);
                }
            }
            __syncthreads();
        }
#pragma unroll
        for (int i = 0; i < 4; ++i) {
#pragma unroll
            for (int j = 0; j < 4; ++j) {
                int n = j * 16 + r16;
#pragma unroll
                for (int r = 0; r < 4; ++r) {
                    int d = wid * 64 + i * 16 + kgrp * 4 + r;
                    VT[d * 64 + n] = f2bf(acc2[i][j][r] + bv[h * 256 + d]);
                }
            }
        }
        __syncthreads();
        // ---- ktv accumulate: C[m][d] += phi(KT) x VT^T over n(=64) ----
#pragma unroll
        for (int kk = 0; kk < 2; ++kk) {
            bf16x8 a[4];
#pragma unroll
            for (int i = 0; i < 4; ++i)
                a[i] = *(const bf16x8*)&KT[(wid * 64 + i * 16 + r16) * 64 + kk * 32 + kgrp * 8];
#pragma unroll
            for (int j = 0; j < 16; ++j) {
                bf16x8 b = *(const bf16x8*)&VT[(j * 16 + r16) * 64 + kk * 32 + kgrp * 8];
#pragma unroll
                for (int i = 0; i < 4; ++i)
                    kacc[i][j] = __builtin_amdgcn_mfma_f32_16x16x32_bf16(a[i], b, kacc[i][j], 0, 0, 0);
            }
        }
        __syncthreads();
    }
    // ---- epilogue: atomic accumulate ktvT[h][d][m] and ksum ----
#pragma unroll
    for (int i = 0; i < 4; ++i) {
#pragma unroll
        for (int j = 0; j < 16; ++j) {
            int d = j * 16 + r16;
#pragma unroll
            for (int r = 0; r < 4; ++r) {
                int m = wid * 64 + i * 16 + kgrp * 4 + r;
                atomicAdd(&ktvT[(size_t)h * 65536 + (size_t)d * 256 + m], kacc[i][j][r]);
            }
        }
    }
    atomicAdd(&ksum[h * 256 + t], ksr);
}

// ---------------- pass 3: q proj + phi + numerator/den + vss(avg) + mean + time ----------------
__global__ __launch_bounds__(256, 1) void pass3_kernel(
    const float* __restrict__ query, const float* __restrict__ src,
    const float* __restrict__ Wq, const float* __restrict__ bq,
    const float* __restrict__ ns_ptr, const u16* __restrict__ ktvb, const float* __restrict__ ksum,
    const u16* __restrict__ Wavg, const float* __restrict__ bavg, float* __restrict__ out)
{
    const int n0 = blockIdx.x * 64;
    const int t = threadIdx.x;
    const int lane = t & 63, wid = t >> 6;
    const int wm = wid >> 1, wn = wid & 1;
    const int r16 = lane & 15, kgrp = lane >> 4;

    __shared__ char smem[132352];
    u16* Xs = (u16*)smem;                       // [64][256] query tile
    u16* Ss = (u16*)(smem + 32768);             // [64][256] source tile
    u16* Qs = (u16*)(smem + 65536);             // [64][256] phi_q tile
    u16* Bs = (u16*)(smem + 98304);             // [256][64] B staging
    float* ksl = (float*)(smem + 131072);       // 256 f32
    float* den = (float*)(smem + 132096);       // 64 f32
    float* outs = (float*)smem;                 // epilogue alias over Xs+Ss (64 KB)

    const float inv_ns = 1.0f / fabsf(ns_ptr[0]);

    // stage query + source tiles
#pragma unroll
    for (int p = 0; p < 8; ++p) {
        int id = p * 256 + t;
        int row = id >> 5, col = (id & 31) * 8;
        int4 wq = {0, 0, 0, 0}, wsrc = {0, 0, 0, 0};
        if (n0 + row < N_NODES) {
            wq   = cvt8(query + ((size_t)(n0 + row) * 256 + col));
            wsrc = cvt8(src   + ((size_t)(n0 + row) * 256 + col));
        }
        *(int4*)&Xs[row * 256 + col] = wq;
        *(int4*)&Ss[row * 256 + col] = wsrc;
    }

    f32x4 oacc[2][8];
#pragma unroll
    for (int i = 0; i < 2; ++i)
#pragma unroll
        for (int j = 0; j < 8; ++j) oacc[i][j] = (f32x4){0.f, 0.f, 0.f, 0.f};

    for (int h = 0; h < NH; ++h) {
        ksl[t] = ksum[h * 256 + t];
        // ---- q-GEMM: C[n 64][m 256] ----
        f32x4 acc[2][8];
#pragma unroll
        for (int i = 0; i < 2; ++i)
#pragma unroll
            for (int j = 0; j < 8; ++j) acc[i][j] = (f32x4){0.f, 0.f, 0.f, 0.f};
        for (int kc = 0; kc < 4; ++kc) {
#pragma unroll
            for (int p = 0; p < 8; ++p) {
                int id = p * 256 + t;
                int m = id >> 3, dc = (id & 7) * 8;
                *(int4*)&Bs[m * 64 + dc] = cvt8(Wq + ((size_t)h * 65536 + (size_t)m * 256 + kc * 64 + dc));
            }
            __syncthreads();
#pragma unroll
            for (int kk = 0; kk < 2; ++kk) {
                bf16x8 a[2];
#pragma unroll
                for (int i = 0; i < 2; ++i)
                    a[i] = *(const bf16x8*)&Xs[(wm * 32 + i * 16 + r16) * 256 + kc * 64 + kk * 32 + kgrp * 8];
#pragma unroll
                for (int j = 0; j < 8; ++j) {
                    bf16x8 b = *(const bf16x8*)&Bs[(wn * 128 + j * 16 + r16) * 64 + kk * 32 + kgrp * 8];
#pragma unroll
                    for (int i = 0; i < 2; ++i)
                        acc[i][j] = __builtin_amdgcn_mfma_f32_16x16x32_bf16(a[i], b, acc[i][j], 0, 0, 0);
                }
            }
            __syncthreads();
        }
        // epilogue: (relu+eps)*inv_ns -> Qs
#pragma unroll
        for (int i = 0; i < 2; ++i) {
#pragma unroll
            for (int j = 0; j < 8; ++j) {
                int c = wn * 128 + j * 16 + r16;
#pragma unroll
                for (int r = 0; r < 4; ++r) {
                    int n = wm * 32 + i * 16 + kgrp * 4 + r;
                    float x = acc[i][j][r] + bq[h * 256 + c];
                    x = (fmaxf(x, 0.f) + FEPS) * inv_ns;
                    Qs[n * 256 + c] = f2bf(x);
                }
            }
        }
        __syncthreads();
        // ---- phi row norms + apply + denominator ----
        {
            int r = t >> 2, q = t & 3;
            float s1 = 0.f, s2 = 0.f;
            bf16x8 v8s[8];
#pragma unroll
            for (int j = 0; j < 8; ++j) {
                v8s[j] = *(const bf16x8*)&Qs[r * 256 + q * 64 + j * 8];
#pragma unroll
                for (int jj = 0; jj < 8; ++jj) {
                    float x = bf2f((u16)v8s[j][jj]);
                    float qq = x * x;
                    s1 += qq; s2 += qq * qq;
                }
            }
            s1 += __shfl_xor(s1, 1, 64); s1 += __shfl_xor(s1, 2, 64);
            s2 += __shfl_xor(s2, 1, 64); s2 += __shfl_xor(s2, 2, 64);
            float sc = (n0 + r < N_NODES) ? sqrtf(s1) / sqrtf(s2) : 0.f;
            float dp = 0.f;
#pragma unroll
            for (int j = 0; j < 8; ++j) {
                bf16x8 w8;
#pragma unroll
                for (int jj = 0; jj < 8; ++jj) {
                    float x = bf2f((u16)v8s[j][jj]);
                    float ph = x * x * sc;
                    u16 pb = f2bf(ph);
                    w8[jj] = (short)pb;
                    dp += bf2f(pb) * ksl[q * 64 + j * 8 + jj];
                }
                *(bf16x8*)&Qs[r * 256 + q * 64 + j * 8] = w8;
            }
            dp += __shfl_xor(dp, 1, 64); dp += __shfl_xor(dp, 2, 64);
            if (q == 0) den[r] = 1.0f / (dp + FEPS);
        }
        __syncthreads();
        // ---- numerator GEMM: C[n][o] = phi_q x ktv[h], B = ktvT_bf[h][o][m] ----
#pragma unroll
        for (int i = 0; i < 2; ++i)
#pragma unroll
            for (int j = 0; j < 8; ++j) acc[i][j] = (f32x4){0.f, 0.f, 0.f, 0.f};
        for (int kc = 0; kc < 4; ++kc) {
#pragma unroll
            for (int p = 0; p < 8; ++p) {
                int id = p * 256 + t;
                int o = id >> 3, mc = (id & 7) * 8;
                *(int4*)&Bs[o * 64 + mc] =
                    *(const int4*)&ktvb[(size_t)h * 65536 + (size_t)o * 256 + kc * 64 + mc];
            }
            __syncthreads();
#pragma unroll
            for (int kk = 0; kk < 2; ++kk) {
                bf16x8 a[2];
#pragma unroll
                for (int i = 0; i < 2; ++i)
                    a[i] = *(const bf16x8*)&Qs[(wm * 32 + i * 16 + r16) * 256 + kc * 64 + kk * 32 + kgrp * 8];
#pragma unroll
                for (int j = 0; j < 8; ++j) {
                    bf16x8 b = *(const bf16x8*)&Bs[(wn * 128 + j * 16 + r16) * 64 + kk * 32 + kgrp * 8];
#pragma unroll
                    for (int i = 0; i < 2; ++i)
                        acc[i][j] = __builtin_amdgcn_mfma_f32_16x16x32_bf16(a[i], b, acc[i][j], 0, 0, 0);
                }
            }
            __syncthreads();
        }
#pragma unroll
        for (int i = 0; i < 2; ++i) {
#pragma unroll
            for (int r = 0; r < 4; ++r) {
                float dr = den[wm * 32 + i * 16 + kgrp * 4 + r];
#pragma unroll
                for (int j = 0; j < 8; ++j)
                    oacc[i][j][r] += acc[i][j][r] * dr;
            }
        }
    }
    // ---- vss GEMM (once): C[n][o] = src x Wavg^T ----
    f32x4 vacc[2][8];
#pragma unroll
    for (int i = 0; i < 2; ++i)
#pragma unroll
        for (int j = 0; j < 8; ++j) vacc[i][j] = (f32x4){0.f, 0.f, 0.f, 0.f};
    for (int kc = 0; kc < 4; ++kc) {
#pragma unroll
        for (int p = 0; p < 8; ++p) {
            int id = p * 256 + t;
            int o = id >> 3, dc = (id & 7) * 8;
            *(int4*)&Bs[o * 64 + dc] = *(const int4*)&Wavg[(size_t)o * 256 + kc * 64 + dc];
        }
        __syncthreads();
#pragma unroll
        for (int kk = 0; kk < 2; ++kk) {
            bf16x8 a[2];
#pragma unroll
            for (int i = 0; i < 2; ++i)
                a[i] = *(const bf16x8*)&Ss[(wm * 32 + i * 16 + r16) * 256 + kc * 64 + kk * 32 + kgrp * 8];
#pragma unroll
            for (int j = 0; j < 8; ++j) {
                bf16x8 b = *(const bf16x8*)&Bs[(wn * 128 + j * 16 + r16) * 64 + kk * 32 + kgrp * 8];
#pragma unroll
                for (int i = 0; i < 2; ++i)
                    vacc[i][j] = __builtin_amdgcn_mfma_f32_16x16x32_bf16(a[i], b, vacc[i][j], 0, 0, 0);
            }
        }
        __syncthreads();
    }
    // ---- mean over heads + vss + bavg into LDS ----
#pragma unroll
    for (int i = 0; i < 2; ++i) {
#pragma unroll
        for (int j = 0; j < 8; ++j) {
            int c = wn * 128 + j * 16 + r16;
            float bo = bavg[c];
#pragma unroll
            for (int r = 0; r < 4; ++r) {
                int n = wm * 32 + i * 16 + kgrp * 4 + r;
                outs[n * 256 + c] = oacc[i][j][r] * 0.125f + vacc[i][j][r] + bo;
            }
        }
    }
    __syncthreads();
    // ---- time component ----
    {
        int r = t >> 2, q = t & 3;
        float s = 0.f;
#pragma unroll
        for (int c4 = 0; c4 < 16; ++c4) {
            float4 v = *(const float4*)&outs[r * 256 + q * 64 + c4 * 4];
            s += v.x * v.x + v.y * v.y + v.z * v.z + v.w * v.w;
        }
        s += __shfl_xor(s, 1, 64);
        s += __shfl_xor(s, 2, 64);
        if (q == 0 && n0 + r < N_NODES)
            out[(size_t)(n0 + r) * 257] = sqrtf(s + 1.0f);
    }
    // ---- space components ----
    for (int rr = 0; rr < 64; ++rr) {
        if (n0 + rr < N_NODES)
            out[(size_t)(n0 + rr) * 257 + 1 + t] = outs[rr * 256 + t];
    }
}

extern "C" void kernel_launch(void* const* d_in, const int* in_sizes, int n_in,
                              void* d_out, int out_size, void* d_ws, size_t ws_size,
                              hipStream_t stream)
{
    const float* query  = (const float*)d_in[0];
    const float* source = (const float*)d_in[1];
    const float* Wq_w   = (const float*)d_in[2];
    const float* Wq_b   = (const float*)d_in[3];
    const float* Wk_w   = (const float*)d_in[4];
    const float* Wk_b   = (const float*)d_in[5];
    const float* Wv_w   = (const float*)d_in[6];
    const float* Wv_b   = (const float*)d_in[7];
    const float* ns     = (const float*)d_in[8];
    const float* vmap_w = (const float*)d_in[9];
    const float* vmap_b = (const float*)d_in[10];
    float* out = (float*)d_out;

    char* ws = (char*)d_ws;
    size_t off = 0;
    auto alloc = [&](size_t bytes) -> char* {
        char* p = ws + off;
        off += (bytes + 255) & ~(size_t)255;
        return p;
    };
    float* ktvT = (float*)alloc((size_t)NH * 65536 * 4);   // [h][d][m] fp32 accum
    float* ksum = (float*)alloc((size_t)NH * 256 * 4);     // adjacent to ktvT for one memset
    u16*   Wavg = (u16*)alloc((size_t)65536 * 2);
    float* bavg = (float*)alloc((size_t)256 * 4);
    u16*   ktvb = (u16*)alloc((size_t)NH * 65536 * 2);

    if (off > ws_size) {
        hipMemsetAsync(d_out, 0x7f, (size_t)out_size * 4, stream);
        return;
    }

    hipMemsetAsync(ktvT, 0, (size_t)NH * 65536 * 4 + (size_t)NH * 256 * 4, stream);

    wavg_kernel<<<64, 256, 0, stream>>>(Wv_w, vmap_w, Wavg);
    bavg_kernel<<<1, 256, 0, stream>>>(vmap_w, Wv_b, vmap_b, bavg);
    pass2_kernel<<<dim3(32, NH), 256, 0, stream>>>(source, Wk_w, Wk_b, Wv_w, Wv_b, ns, ktvT, ksum);
    f2bf4_kernel<<<512, 256, 0, stream>>>(ktvT, ktvb, NH * 65536 / 4);
    pass3_kernel<<<313, 256, 0, stream>>>(query, source, Wq_w, Wq_b, ns, ktvb, ksum, Wavg, bavg, out);
}

// Round 4
// 1065.410 us; speedup vs baseline: 1.2634x; 1.2634x over previous
//
#include <hip/hip_runtime.h>
#include <hip/hip_bf16.h>

#define N_NODES 20000
#define NH      8
#define GSZ     625     // nodes per pass-2 group (32 groups * 625 = 20000)
#define NTILES  10      // ceil(625/64)
#define FEPS    1e-6f
#define XS_LD   264     // padded stride for [64][256] bf16 tiles (row step 528B = 4 mod 32 banks)
#define TL      72      // padded stride for [256][64] bf16 tiles (row step 144B = 4 mod 32 banks)

typedef __attribute__((ext_vector_type(8))) short bf16x8;
typedef __attribute__((ext_vector_type(4))) float f32x4;
typedef unsigned short u16;

__device__ __forceinline__ float bf2f(u16 u) {
    union { unsigned int i; float f; } v; v.i = ((unsigned int)u) << 16; return v.f;
}
__device__ __forceinline__ u16 f2bf(float f) {
    union { float f; unsigned int i; } v; v.f = f;
    return (u16)((v.i + 0x7fffu + ((v.i >> 16) & 1u)) >> 16);
}
__device__ __forceinline__ int pk2(float a, float b) {
    return (int)f2bf(a) | ((int)f2bf(b) << 16);
}
// convert 8 consecutive fp32 -> 8 bf16 packed in int4
__device__ __forceinline__ int4 cvt8(const float* __restrict__ s) {
    float4 a = *(const float4*)s;
    float4 b = *(const float4*)(s + 4);
    int4 w;
    w.x = pk2(a.x, a.y); w.y = pk2(a.z, a.w);
    w.z = pk2(b.x, b.y); w.w = pk2(b.z, b.w);
    return w;
}

// ---------------- fp32 -> bf16 convert (vectorized x4) ----------------
__global__ void f2bf4_kernel(const float* __restrict__ src, u16* __restrict__ dst, int n4) {
    int i = blockIdx.x * blockDim.x + threadIdx.x;
    if (i >= n4) return;
    float4 v = reinterpret_cast<const float4*>(src)[i];
    ushort4 o;
    o.x = f2bf(v.x); o.y = f2bf(v.y); o.z = f2bf(v.z); o.w = f2bf(v.w);
    reinterpret_cast<ushort4*>(dst)[i] = o;
}

// ---------------- Wavg[o][d] = (1/8) sum_h sum_e vmap[o,e] * Wv[h,e,d] ----------------
__global__ __launch_bounds__(256) void wavg_kernel(const float* __restrict__ Wv,
                                                   const float* __restrict__ vmap_w,
                                                   u16* __restrict__ Wavg)
{
    const int o = blockIdx.x, t = threadIdx.x;
    __shared__ float vml[256];
    vml[t] = vmap_w[(size_t)o * 256 + t];
    __syncthreads();
    float acc = 0.f;
    for (int h = 0; h < NH; ++h) {
        const float* Wh = Wv + (size_t)h * 65536 + t;
#pragma unroll 4
        for (int e = 0; e < 256; ++e)
            acc += vml[e] * Wh[(size_t)e * 256];
    }
    Wavg[(size_t)o * 256 + t] = f2bf(acc * 0.125f);
}

// ---------------- bavg[o] = vmap_b[o] + sum_e vmap[o,e] * (1/8 sum_h bv[h,e]) ----------------
__global__ __launch_bounds__(256) void bavg_kernel(const float* __restrict__ vmap_w,
                                                   const float* __restrict__ bv,
                                                   const float* __restrict__ vmap_b,
                                                   float* __restrict__ bavg)
{
    __shared__ float bva[256];
    const int t = threadIdx.x;
    float s = 0.f;
    for (int h = 0; h < NH; ++h) s += bv[h * 256 + t];
    bva[t] = s * 0.125f;
    __syncthreads();
    float acc = vmap_b[t];
    for (int e = 0; e < 256; ++e) acc += vmap_w[(size_t)t * 256 + e] * bva[e];
    bavg[t] = acc;
}

// ---------------- pass 2: fused K/V proj + phi + ktv/ksum accumulation ----------------
// h = bid&7 -> all blocks of one head land on one XCD (round-robin dispatch) -> weights L2-resident
__global__ __launch_bounds__(256, 1) void pass2_kernel(
    const float* __restrict__ srcf, const u16* __restrict__ srcb, const int use_bf,
    const u16* __restrict__ Wkb, const float* __restrict__ bk,
    const u16* __restrict__ Wvb, const float* __restrict__ bv,
    const float* __restrict__ ns_ptr,
    float* __restrict__ ktvT, float* __restrict__ ksum)
{
    const int bid = blockIdx.x;
    const int h = bid & 7, g = bid >> 3;
    const int t = threadIdx.x;
    const int lane = t & 63, wid = t >> 6;
    const int r16 = lane & 15, kgrp = lane >> 4;

    __shared__ u16 Xs[64 * XS_LD];   // [n][d] padded
    __shared__ u16 KT[256 * TL];     // [m][n] padded (k', then phi)
    __shared__ u16 VT[256 * TL];     // [d][n] padded
    __shared__ float red[512];
    __shared__ float scl[64];

    const float inv_ns = 1.0f / fabsf(ns_ptr[0]);
    const u16* Wkh = Wkb + (size_t)h * 65536;
    const u16* Wvh = Wvb + (size_t)h * 65536;

    f32x4 kacc[4][16];
#pragma unroll
    for (int i = 0; i < 4; ++i)
#pragma unroll
        for (int j = 0; j < 16; ++j) kacc[i][j] = (f32x4){0.f, 0.f, 0.f, 0.f};
    float ksr = 0.f;

    for (int it = 0; it < NTILES; ++it) {
        const int ln0 = it * 64;
        // ---- stage X tile ----
#pragma unroll
        for (int p = 0; p < 8; ++p) {
            int id = p * 256 + t;
            int row = id >> 5, col = (id & 31) * 8;
            int4 w = {0, 0, 0, 0};
            if (ln0 + row < GSZ) {
                size_t gofs = (size_t)(g * GSZ + ln0 + row) * 256 + col;
                w = use_bf ? *(const int4*)&srcb[gofs] : cvt8(srcf + gofs);
            }
            *(int4*)&Xs[row * XS_LD + col] = w;
        }
        __syncthreads();

        f32x4 acc2[4][4];
        // ---- K-GEMM: C[m 256][n 64], weights direct from L2 ----
#pragma unroll
        for (int i = 0; i < 4; ++i)
#pragma unroll
            for (int j = 0; j < 4; ++j) acc2[i][j] = (f32x4){0.f, 0.f, 0.f, 0.f};
#pragma unroll
        for (int kc = 0; kc < 4; ++kc) {
#pragma unroll
            for (int kk = 0; kk < 2; ++kk) {
                bf16x8 a[4];
#pragma unroll
                for (int i = 0; i < 4; ++i)
                    a[i] = *(const bf16x8*)&Wkh[(size_t)(wid * 64 + i * 16 + r16) * 256 + kc * 64 + kk * 32 + kgrp * 8];
#pragma unroll
                for (int j = 0; j < 4; ++j) {
                    bf16x8 b = *(const bf16x8*)&Xs[(j * 16 + r16) * XS_LD + kc * 64 + kk * 32 + kgrp * 8];
#pragma unroll
                    for (int i = 0; i < 4; ++i)
                        acc2[i][j] = __builtin_amdgcn_mfma_f32_16x16x32_bf16(a[i], b, acc2[i][j], 0, 0, 0);
                }
            }
        }
        // epilogue -> KT (relu + eps) * inv_ns
#pragma unroll
        for (int i = 0; i < 4; ++i) {
#pragma unroll
            for (int j = 0; j < 4; ++j) {
                int n = j * 16 + r16;
#pragma unroll
                for (int r = 0; r < 4; ++r) {
                    int m = wid * 64 + i * 16 + kgrp * 4 + r;
                    float x = acc2[i][j][r] + bk[h * 256 + m];
                    x = (fmaxf(x, 0.f) + FEPS) * inv_ns;
                    KT[m * TL + n] = f2bf(x);
                }
            }
        }
        __syncthreads();
        // ---- column reductions per node: s1 = sum_m k'^2, s2 = sum_m k'^4 ----
        {
            int c = t & 63, ch = t >> 6;
            float s1 = 0.f, s2 = 0.f;
#pragma unroll
            for (int i = 0; i < 64; ++i) {
                float x = bf2f(KT[(ch * 64 + i) * TL + c]);
                float q = x * x;
                s1 += q; s2 += q * q;
            }
            red[ch * 64 + c] = s1;
            red[256 + ch * 64 + c] = s2;
        }
        __syncthreads();
        if (t < 64) {
            float s1 = red[t] + red[64 + t] + red[128 + t] + red[192 + t];
            float s2 = red[256 + t] + red[320 + t] + red[384 + t] + red[448 + t];
            scl[t] = (ln0 + t < GSZ) ? sqrtf(s1) / sqrtf(s2) : 0.f;
        }
        __syncthreads();
        // ---- phi in place (row m = t) + ksum accumulation ----
        {
            float kp = 0.f;
#pragma unroll
            for (int j = 0; j < 8; ++j) {
                bf16x8 v8 = *(const bf16x8*)&KT[t * TL + j * 8];
                bf16x8 w8;
#pragma unroll
                for (int jj = 0; jj < 8; ++jj) {
                    float x = bf2f((u16)v8[jj]);
                    float ph = x * x * scl[j * 8 + jj];
                    u16 pb = f2bf(ph);
                    w8[jj] = (short)pb;
                    kp += bf2f(pb);
                }
                *(bf16x8*)&KT[t * TL + j * 8] = w8;
            }
            ksr += kp;
        }
        // ---- V-GEMM: C[d 256][n 64] ----
#pragma unroll
        for (int i = 0; i < 4; ++i)
#pragma unroll
            for (int j = 0; j < 4; ++j) acc2[i][j] = (f32x4){0.f, 0.f, 0.f, 0.f};
#pragma unroll
        for (int kc = 0; kc < 4; ++kc) {
#pragma unroll
            for (int kk = 0; kk < 2; ++kk) {
                bf16x8 a[4];
#pragma unroll
                for (int i = 0; i < 4; ++i)
                    a[i] = *(const bf16x8*)&Wvh[(size_t)(wid * 64 + i * 16 + r16) * 256 + kc * 64 + kk * 32 + kgrp * 8];
#pragma unroll
                for (int j = 0; j < 4; ++j) {
                    bf16x8 b = *(const bf16x8*)&Xs[(j * 16 + r16) * XS_LD + kc * 64 + kk * 32 + kgrp * 8];
#pragma unroll
                    for (int i = 0; i < 4; ++i)
                        acc2[i][j] = __builtin_amdgcn_mfma_f32_16x16x32_bf16(a[i], b, acc2[i][j], 0, 0, 0);
                }
            }
        }
#pragma unroll
        for (int i = 0; i < 4; ++i) {
#pragma unroll
            for (int j = 0; j < 4; ++j) {
                int n = j * 16 + r16;
#pragma unroll
                for (int r = 0; r < 4; ++r) {
                    int d = wid * 64 + i * 16 + kgrp * 4 + r;
                    VT[d * TL + n] = f2bf(acc2[i][j][r] + bv[h * 256 + d]);
                }
            }
        }
        __syncthreads();
        // ---- ktv accumulate: C[m][d] += phi(KT) x VT over n(=64) ----
#pragma unroll
        for (int kk = 0; kk < 2; ++kk) {
            bf16x8 a[4];
#pragma unroll
            for (int i = 0; i < 4; ++i)
                a[i] = *(const bf16x8*)&KT[(wid * 64 + i * 16 + r16) * TL + kk * 32 + kgrp * 8];
#pragma unroll
            for (int j = 0; j < 16; ++j) {
                bf16x8 b = *(const bf16x8*)&VT[(j * 16 + r16) * TL + kk * 32 + kgrp * 8];
#pragma unroll
                for (int i = 0; i < 4; ++i)
                    kacc[i][j] = __builtin_amdgcn_mfma_f32_16x16x32_bf16(a[i], b, kacc[i][j], 0, 0, 0);
            }
        }
        __syncthreads();
    }
    // ---- epilogue: atomic accumulate ktvT[h][d][m] and ksum (same-XCD L2 atomics) ----
#pragma unroll
    for (int i = 0; i < 4; ++i) {
#pragma unroll
        for (int j = 0; j < 16; ++j) {
            int d = j * 16 + r16;
#pragma unroll
            for (int r = 0; r < 4; ++r) {
                int m = wid * 64 + i * 16 + kgrp * 4 + r;
                atomicAdd(&ktvT[(size_t)h * 65536 + (size_t)d * 256 + m], kacc[i][j][r]);
            }
        }
    }
    atomicAdd(&ksum[h * 256 + t], ksr);
}

// ---------------- pass 3: q proj + phi + numerator/den + vss(avg) + mean + time ----------------
__global__ __launch_bounds__(256, 1) void pass3_kernel(
    const float* __restrict__ qf, const u16* __restrict__ qb,
    const float* __restrict__ sf, const u16* __restrict__ sb, const int use_bf,
    const u16* __restrict__ Wqb, const float* __restrict__ bq,
    const float* __restrict__ ns_ptr, const u16* __restrict__ ktvb, const float* __restrict__ ksum,
    const u16* __restrict__ Wavg, const float* __restrict__ bavg, float* __restrict__ out)
{
    const int n0 = blockIdx.x * 64;
    const int t = threadIdx.x;
    const int lane = t & 63, wid = t >> 6;
    const int wm = wid >> 1, wn = wid & 1;
    const int r16 = lane & 15, kgrp = lane >> 4;

    __shared__ char smem[103680];
    u16* Xs = (u16*)smem;                       // [64][XS_LD] query tile  (33792 B)
    u16* Ss = (u16*)(smem + 33792);             // [64][XS_LD] source tile (33792 B)
    u16* Qs = (u16*)(smem + 67584);             // [64][XS_LD] phi_q tile  (33792 B)
    float* ksl = (float*)(smem + 101376);       // 256 f32
    float* den = (float*)(smem + 102400);       // 64 f32
    float* outs = (float*)smem;                 // epilogue alias over Xs+Ss (65536 B)

    const float inv_ns = 1.0f / fabsf(ns_ptr[0]);

    // stage query + source tiles
#pragma unroll
    for (int p = 0; p < 8; ++p) {
        int id = p * 256 + t;
        int row = id >> 5, col = (id & 31) * 8;
        int4 wq = {0, 0, 0, 0}, wsrc = {0, 0, 0, 0};
        if (n0 + row < N_NODES) {
            size_t gofs = (size_t)(n0 + row) * 256 + col;
            if (use_bf) {
                wq   = *(const int4*)&qb[gofs];
                wsrc = *(const int4*)&sb[gofs];
            } else {
                wq   = cvt8(qf + gofs);
                wsrc = cvt8(sf + gofs);
            }
        }
        *(int4*)&Xs[row * XS_LD + col] = wq;
        *(int4*)&Ss[row * XS_LD + col] = wsrc;
    }
    __syncthreads();

    f32x4 oacc[2][8];
#pragma unroll
    for (int i = 0; i < 2; ++i)
#pragma unroll
        for (int j = 0; j < 8; ++j) oacc[i][j] = (f32x4){0.f, 0.f, 0.f, 0.f};

    for (int h = 0; h < NH; ++h) {
        ksl[t] = ksum[h * 256 + t];
        // ---- q-GEMM: C[n 64][m 256], Wq direct from L2 ----
        f32x4 acc[2][8];
#pragma unroll
        for (int i = 0; i < 2; ++i)
#pragma unroll
            for (int j = 0; j < 8; ++j) acc[i][j] = (f32x4){0.f, 0.f, 0.f, 0.f};
#pragma unroll
        for (int kc = 0; kc < 4; ++kc) {
#pragma unroll
            for (int kk = 0; kk < 2; ++kk) {
                bf16x8 a[2];
#pragma unroll
                for (int i = 0; i < 2; ++i)
                    a[i] = *(const bf16x8*)&Xs[(wm * 32 + i * 16 + r16) * XS_LD + kc * 64 + kk * 32 + kgrp * 8];
#pragma unroll
                for (int j = 0; j < 8; ++j) {
                    bf16x8 b = *(const bf16x8*)&Wqb[(size_t)h * 65536 +
                        (size_t)(wn * 128 + j * 16 + r16) * 256 + kc * 64 + kk * 32 + kgrp * 8];
#pragma unroll
                    for (int i = 0; i < 2; ++i)
                        acc[i][j] = __builtin_amdgcn_mfma_f32_16x16x32_bf16(a[i], b, acc[i][j], 0, 0, 0);
                }
            }
        }
        __syncthreads();   // prev head's numerator reads of Qs done
        // epilogue: (relu+eps)*inv_ns -> Qs
#pragma unroll
        for (int i = 0; i < 2; ++i) {
#pragma unroll
            for (int j = 0; j < 8; ++j) {
                int c = wn * 128 + j * 16 + r16;
#pragma unroll
                for (int r = 0; r < 4; ++r) {
                    int n = wm * 32 + i * 16 + kgrp * 4 + r;
                    float x = acc[i][j][r] + bq[h * 256 + c];
                    x = (fmaxf(x, 0.f) + FEPS) * inv_ns;
                    Qs[n * XS_LD + c] = f2bf(x);
                }
            }
        }
        __syncthreads();   // Qs + ksl visible
        // ---- phi row norms + apply + denominator ----
        {
            int r = t >> 2, q = t & 3;
            float s1 = 0.f, s2 = 0.f;
            bf16x8 v8s[8];
#pragma unroll
            for (int j = 0; j < 8; ++j) {
                v8s[j] = *(const bf16x8*)&Qs[r * XS_LD + q * 64 + j * 8];
#pragma unroll
                for (int jj = 0; jj < 8; ++jj) {
                    float x = bf2f((u16)v8s[j][jj]);
                    float qq = x * x;
                    s1 += qq; s2 += qq * qq;
                }
            }
            s1 += __shfl_xor(s1, 1, 64); s1 += __shfl_xor(s1, 2, 64);
            s2 += __shfl_xor(s2, 1, 64); s2 += __shfl_xor(s2, 2, 64);
            float sc = (n0 + r < N_NODES) ? sqrtf(s1) / sqrtf(s2) : 0.f;
            float dp = 0.f;
#pragma unroll
            for (int j = 0; j < 8; ++j) {
                bf16x8 w8;
#pragma unroll
                for (int jj = 0; jj < 8; ++jj) {
                    float x = bf2f((u16)v8s[j][jj]);
                    float ph = x * x * sc;
                    u16 pb = f2bf(ph);
                    w8[jj] = (short)pb;
                    dp += bf2f(pb) * ksl[q * 64 + j * 8 + jj];
                }
                *(bf16x8*)&Qs[r * XS_LD + q * 64 + j * 8] = w8;
            }
            dp += __shfl_xor(dp, 1, 64); dp += __shfl_xor(dp, 2, 64);
            if (q == 0) den[r] = 1.0f / (dp + FEPS);
        }
        __syncthreads();   // phi'd Qs + den visible
        // ---- numerator GEMM: C[n][o] = phi_q x ktv[h], ktvb direct from L2 ----
#pragma unroll
        for (int i = 0; i < 2; ++i)
#pragma unroll
            for (int j = 0; j < 8; ++j) acc[i][j] = (f32x4){0.f, 0.f, 0.f, 0.f};
#pragma unroll
        for (int kc = 0; kc < 4; ++kc) {
#pragma unroll
            for (int kk = 0; kk < 2; ++kk) {
                bf16x8 a[2];
#pragma unroll
                for (int i = 0; i < 2; ++i)
                    a[i] = *(const bf16x8*)&Qs[(wm * 32 + i * 16 + r16) * XS_LD + kc * 64 + kk * 32 + kgrp * 8];
#pragma unroll
                for (int j = 0; j < 8; ++j) {
                    bf16x8 b = *(const bf16x8*)&ktvb[(size_t)h * 65536 +
                        (size_t)(wn * 128 + j * 16 + r16) * 256 + kc * 64 + kk * 32 + kgrp * 8];
#pragma unroll
                    for (int i = 0; i < 2; ++i)
                        acc[i][j] = __builtin_amdgcn_mfma_f32_16x16x32_bf16(a[i], b, acc[i][j], 0, 0, 0);
                }
            }
        }
#pragma unroll
        for (int i = 0; i < 2; ++i) {
#pragma unroll
            for (int r = 0; r < 4; ++r) {
                float dr = den[wm * 32 + i * 16 + kgrp * 4 + r];
#pragma unroll
                for (int j = 0; j < 8; ++j)
                    oacc[i][j][r] += acc[i][j][r] * dr;
            }
        }
    }
    // ---- vss GEMM (once): C[n][o] = src x Wavg^T, Wavg direct from L2 ----
    f32x4 vacc[2][8];
#pragma unroll
    for (int i = 0; i < 2; ++i)
#pragma unroll
        for (int j = 0; j < 8; ++j) vacc[i][j] = (f32x4){0.f, 0.f, 0.f, 0.f};
#pragma unroll
    for (int kc = 0; kc < 4; ++kc) {
#pragma unroll
        for (int kk = 0; kk < 2; ++kk) {
            bf16x8 a[2];
#pragma unroll
            for (int i = 0; i < 2; ++i)
                a[i] = *(const bf16x8*)&Ss[(wm * 32 + i * 16 + r16) * XS_LD + kc * 64 + kk * 32 + kgrp * 8];
#pragma unroll
            for (int j = 0; j < 8; ++j) {
                bf16x8 b = *(const bf16x8*)&Wavg[(size_t)(wn * 128 + j * 16 + r16) * 256 + kc * 64 + kk * 32 + kgrp * 8];
#pragma unroll
                for (int i = 0; i < 2; ++i)
                    vacc[i][j] = __builtin_amdgcn_mfma_f32_16x16x32_bf16(a[i], b, vacc[i][j], 0, 0, 0);
            }
        }
    }
    __syncthreads();   // Ss reads done before outs alias writes
    // ---- mean over heads + vss + bavg into LDS ----
#pragma unroll
    for (int i = 0; i < 2; ++i) {
#pragma unroll
        for (int j = 0; j < 8; ++j) {
            int c = wn * 128 + j * 16 + r16;
            float bo = bavg[c];
#pragma unroll
            for (int r = 0; r < 4; ++r) {
                int n = wm * 32 + i * 16 + kgrp * 4 + r;
                outs[n * 256 + c] = oacc[i][j][r] * 0.125f + vacc[i][j][r] + bo;
            }
        }
    }
    __syncthreads();
    // ---- time component ----
    {
        int r = t >> 2, q = t & 3;
        float s = 0.f;
#pragma unroll
        for (int c4 = 0; c4 < 16; ++c4) {
            float4 v = *(const float4*)&outs[r * 256 + q * 64 + c4 * 4];
            s += v.x * v.x + v.y * v.y + v.z * v.z + v.w * v.w;
        }
        s += __shfl_xor(s, 1, 64);
        s += __shfl_xor(s, 2, 64);
        if (q == 0 && n0 + r < N_NODES)
            out[(size_t)(n0 + r) * 257] = sqrtf(s + 1.0f);
    }
    // ---- space components ----
    for (int rr = 0; rr < 64; ++rr) {
        if (n0 + rr < N_NODES)
            out[(size_t)(n0 + rr) * 257 + 1 + t] = outs[rr * 256 + t];
    }
}

extern "C" void kernel_launch(void* const* d_in, const int* in_sizes, int n_in,
                              void* d_out, int out_size, void* d_ws, size_t ws_size,
                              hipStream_t stream)
{
    const float* query  = (const float*)d_in[0];
    const float* source = (const float*)d_in[1];
    const float* Wq_w   = (const float*)d_in[2];
    const float* Wq_b   = (const float*)d_in[3];
    const float* Wk_w   = (const float*)d_in[4];
    const float* Wk_b   = (const float*)d_in[5];
    const float* Wv_w   = (const float*)d_in[6];
    const float* Wv_b   = (const float*)d_in[7];
    const float* ns     = (const float*)d_in[8];
    const float* vmap_w = (const float*)d_in[9];
    const float* vmap_b = (const float*)d_in[10];
    float* out = (float*)d_out;

    char* ws = (char*)d_ws;
    size_t off = 0;
    auto alloc = [&](size_t bytes) -> char* {
        char* p = ws + off;
        off += (bytes + 255) & ~(size_t)255;
        return p;
    };
    float* ktvT = (float*)alloc((size_t)NH * 65536 * 4);   // [h][d][m] fp32 accum
    float* ksum = (float*)alloc((size_t)NH * 256 * 4);     // adjacent for one memset
    u16*   Wqb  = (u16*)alloc((size_t)NH * 65536 * 2);
    u16*   Wkb  = (u16*)alloc((size_t)NH * 65536 * 2);
    u16*   Wvb  = (u16*)alloc((size_t)NH * 65536 * 2);
    u16*   Wavg = (u16*)alloc((size_t)65536 * 2);
    float* bavg = (float*)alloc((size_t)256 * 4);
    u16*   ktvb = (u16*)alloc((size_t)NH * 65536 * 2);
    size_t base_need = off;

    // optional bf16 source/query copies
    u16* qbf = (u16*)alloc((size_t)N_NODES * 256 * 2);
    u16* sbf = (u16*)alloc((size_t)N_NODES * 256 * 2);
    int use_bf = (off <= ws_size) ? 1 : 0;

    if (base_need > ws_size) {
        hipMemsetAsync(d_out, 0x7f, (size_t)out_size * 4, stream);
        return;
    }

    hipMemsetAsync(ktvT, 0, (size_t)NH * 65536 * 4 + (size_t)NH * 256 * 4, stream);

    // weight conversions (131072 float4s each)
    f2bf4_kernel<<<512, 256, 0, stream>>>(Wq_w, Wqb, NH * 65536 / 4);
    f2bf4_kernel<<<512, 256, 0, stream>>>(Wk_w, Wkb, NH * 65536 / 4);
    f2bf4_kernel<<<512, 256, 0, stream>>>(Wv_w, Wvb, NH * 65536 / 4);
    if (use_bf) {
        f2bf4_kernel<<<5000, 256, 0, stream>>>(query, qbf, N_NODES * 256 / 4);
        f2bf4_kernel<<<5000, 256, 0, stream>>>(source, sbf, N_NODES * 256 / 4);
    }
    wavg_kernel<<<256, 256, 0, stream>>>(Wv_w, vmap_w, Wavg);
    bavg_kernel<<<1, 256, 0, stream>>>(vmap_w, Wv_b, vmap_b, bavg);

    pass2_kernel<<<256, 256, 0, stream>>>(source, sbf, use_bf, Wkb, Wk_b, Wvb, Wv_b, ns, ktvT, ksum);
    f2bf4_kernel<<<512, 256, 0, stream>>>(ktvT, ktvb, NH * 65536 / 4);
    pass3_kernel<<<313, 256, 0, stream>>>(query, qbf, source, sbf, use_bf,
                                          Wqb, Wq_b, ns, ktvb, ksum, Wavg, bavg, out);
}

// Round 5
// 702.211 us; speedup vs baseline: 1.9169x; 1.5172x over previous
//
#include <hip/hip_runtime.h>
#include <hip/hip_bf16.h>

#define N_NODES 20000
#define NH      8
#define GSZ     625     // nodes per pass-2 group (32 groups * 625 = 20000)
#define NTILES  10      // ceil(625/64)
#define FEPS    1e-6f
#define XS_LD   264     // padded stride for [*][256] bf16 tiles
#define TL      72      // padded stride for [256][64] bf16 tiles
#define P3R     80      // pass-3 rows per block (250 * 80 = 20000 exactly)

typedef __attribute__((ext_vector_type(8))) short bf16x8;
typedef __attribute__((ext_vector_type(4))) float f32x4;
typedef unsigned short u16;

__device__ __forceinline__ float bf2f(u16 u) {
    union { unsigned int i; float f; } v; v.i = ((unsigned int)u) << 16; return v.f;
}
__device__ __forceinline__ u16 f2bf(float f) {
    union { float f; unsigned int i; } v; v.f = f;
    return (u16)((v.i + 0x7fffu + ((v.i >> 16) & 1u)) >> 16);
}
__device__ __forceinline__ int pk2(float a, float b) {
    return (int)f2bf(a) | ((int)f2bf(b) << 16);
}
__device__ __forceinline__ int4 cvt8(const float* __restrict__ s) {
    float4 a = *(const float4*)s;
    float4 b = *(const float4*)(s + 4);
    int4 w;
    w.x = pk2(a.x, a.y); w.y = pk2(a.z, a.w);
    w.z = pk2(b.x, b.y); w.w = pk2(b.z, b.w);
    return w;
}

// ---------------- fp32 -> bf16 convert (vectorized x4) ----------------
__global__ void f2bf4_kernel(const float* __restrict__ src, u16* __restrict__ dst, int n4) {
    int i = blockIdx.x * blockDim.x + threadIdx.x;
    if (i >= n4) return;
    float4 v = reinterpret_cast<const float4*>(src)[i];
    ushort4 o;
    o.x = f2bf(v.x); o.y = f2bf(v.y); o.z = f2bf(v.z); o.w = f2bf(v.w);
    reinterpret_cast<ushort4*>(dst)[i] = o;
}

// ---------------- Wavg[o][d] = (1/8) sum_h sum_e vmap[o,e] * Wv[h,e,d] ----------------
__global__ __launch_bounds__(256) void wavg_kernel(const float* __restrict__ Wv,
                                                   const float* __restrict__ vmap_w,
                                                   u16* __restrict__ Wavg)
{
    const int o = blockIdx.x, t = threadIdx.x;
    __shared__ float vml[256];
    vml[t] = vmap_w[(size_t)o * 256 + t];
    __syncthreads();
    float acc = 0.f;
    for (int h = 0; h < NH; ++h) {
        const float* Wh = Wv + (size_t)h * 65536 + t;
#pragma unroll 4
        for (int e = 0; e < 256; ++e)
            acc += vml[e] * Wh[(size_t)e * 256];
    }
    Wavg[(size_t)o * 256 + t] = f2bf(acc * 0.125f);
}

// ---------------- bavg[o] = vmap_b[o] + sum_e vmap[o,e] * (1/8 sum_h bv[h,e]) ----------------
__global__ __launch_bounds__(256) void bavg_kernel(const float* __restrict__ vmap_w,
                                                   const float* __restrict__ bv,
                                                   const float* __restrict__ vmap_b,
                                                   float* __restrict__ bavg)
{
    __shared__ float bva[256];
    const int t = threadIdx.x;
    float s = 0.f;
    for (int h = 0; h < NH; ++h) s += bv[h * 256 + t];
    bva[t] = s * 0.125f;
    __syncthreads();
    float acc = vmap_b[t];
    for (int e = 0; e < 256; ++e) acc += vmap_w[(size_t)t * 256 + e] * bva[e];
    bavg[t] = acc;
}

// ---------------- pass 2: fused K/V proj + phi + ktv/ksum accumulation (512 thr, 8 waves) ----------------
__global__ __launch_bounds__(512, 2) void pass2_kernel(
    const float* __restrict__ srcf, const u16* __restrict__ srcb, const int use_bf,
    const u16* __restrict__ Wkb, const float* __restrict__ bk,
    const u16* __restrict__ Wvb, const float* __restrict__ bv,
    const float* __restrict__ ns_ptr,
    float* __restrict__ ktvT, float* __restrict__ ksum)
{
    const int bid = blockIdx.x;
    const int h = bid & 7, g = bid >> 3;
    const int t = threadIdx.x;
    const int lane = t & 63, wid = t >> 6;      // 8 waves
    const int r16 = lane & 15, kgrp = lane >> 4;

    __shared__ char smem[111872 + 256];
    u16* Xs = (u16*)smem;                        // [64][XS_LD]  33792 B
    u16* KT = (u16*)(smem + 33792);              // [256][TL]    36864 B
    u16* VT = (u16*)(smem + 70656);              // [256][TL]    36864 B
    float* red = (float*)(smem + 107520);        // 1024 f32
    float* scl = (float*)(smem + 111616);        // 64 f32

    const float inv_ns = 1.0f / fabsf(ns_ptr[0]);
    const u16* Wkh = Wkb + (size_t)h * 65536;
    const u16* Wvh = Wvb + (size_t)h * 65536;

    f32x4 kacc[2][16];
#pragma unroll
    for (int i = 0; i < 2; ++i)
#pragma unroll
        for (int j = 0; j < 16; ++j) kacc[i][j] = (f32x4){0.f, 0.f, 0.f, 0.f};
    float ksr = 0.f;

    for (int it = 0; it < NTILES; ++it) {
        const int ln0 = it * 64;
        // ---- stage X tile (2048 int4) ----
#pragma unroll
        for (int p = 0; p < 4; ++p) {
            int id = p * 512 + t;
            int row = id >> 5, col = (id & 31) * 8;
            int4 w = {0, 0, 0, 0};
            if (ln0 + row < GSZ) {
                size_t gofs = (size_t)(g * GSZ + ln0 + row) * 256 + col;
                w = use_bf ? *(const int4*)&srcb[gofs] : cvt8(srcf + gofs);
            }
            *(int4*)&Xs[row * XS_LD + col] = w;
        }
        __syncthreads();

        f32x4 acc2[2][4];
        // ---- K-GEMM: C[m 256][n 64], wave m-range = wid*32 ----
#pragma unroll
        for (int i = 0; i < 2; ++i)
#pragma unroll
            for (int j = 0; j < 4; ++j) acc2[i][j] = (f32x4){0.f, 0.f, 0.f, 0.f};
#pragma unroll
        for (int kc = 0; kc < 4; ++kc) {
#pragma unroll
            for (int kk = 0; kk < 2; ++kk) {
                bf16x8 a[2];
#pragma unroll
                for (int i = 0; i < 2; ++i)
                    a[i] = *(const bf16x8*)&Wkh[(size_t)(wid * 32 + i * 16 + r16) * 256 + kc * 64 + kk * 32 + kgrp * 8];
#pragma unroll
                for (int j = 0; j < 4; ++j) {
                    bf16x8 b = *(const bf16x8*)&Xs[(j * 16 + r16) * XS_LD + kc * 64 + kk * 32 + kgrp * 8];
#pragma unroll
                    for (int i = 0; i < 2; ++i)
                        acc2[i][j] = __builtin_amdgcn_mfma_f32_16x16x32_bf16(a[i], b, acc2[i][j], 0, 0, 0);
                }
            }
        }
        // epilogue -> KT (relu + eps) * inv_ns
#pragma unroll
        for (int i = 0; i < 2; ++i) {
#pragma unroll
            for (int j = 0; j < 4; ++j) {
                int n = j * 16 + r16;
#pragma unroll
                for (int r = 0; r < 4; ++r) {
                    int m = wid * 32 + i * 16 + kgrp * 4 + r;
                    float x = acc2[i][j][r] + bk[h * 256 + m];
                    x = (fmaxf(x, 0.f) + FEPS) * inv_ns;
                    KT[m * TL + n] = f2bf(x);
                }
            }
        }
        __syncthreads();
        // ---- column reductions per node ----
        {
            int c = t & 63, ch = t >> 6;
            float s1 = 0.f, s2 = 0.f;
#pragma unroll
            for (int i = 0; i < 32; ++i) {
                float x = bf2f(KT[(ch * 32 + i) * TL + c]);
                float q = x * x;
                s1 += q; s2 += q * q;
            }
            red[ch * 64 + c] = s1;
            red[512 + ch * 64 + c] = s2;
        }
        __syncthreads();
        if (t < 64) {
            float s1 = 0.f, s2 = 0.f;
#pragma unroll
            for (int ch = 0; ch < 8; ++ch) {
                s1 += red[ch * 64 + t];
                s2 += red[512 + ch * 64 + t];
            }
            scl[t] = (ln0 + t < GSZ) ? sqrtf(s1) / sqrtf(s2) : 0.f;
        }
        __syncthreads();
        // ---- phi in place (row m = t>>1, half n-range) + ksum partial ----
        {
            const int m = t >> 1, q0 = (t & 1) * 32;
            float kp = 0.f;
#pragma unroll
            for (int j = 0; j < 4; ++j) {
                bf16x8 v8 = *(const bf16x8*)&KT[m * TL + q0 + j * 8];
                bf16x8 w8;
#pragma unroll
                for (int jj = 0; jj < 8; ++jj) {
                    float x = bf2f((u16)v8[jj]);
                    float ph = x * x * scl[q0 + j * 8 + jj];
                    u16 pb = f2bf(ph);
                    w8[jj] = (short)pb;
                    kp += bf2f(pb);
                }
                *(bf16x8*)&KT[m * TL + q0 + j * 8] = w8;
            }
            ksr += kp;
        }
        // ---- V-GEMM: C[d 256][n 64] ----
#pragma unroll
        for (int i = 0; i < 2; ++i)
#pragma unroll
            for (int j = 0; j < 4; ++j) acc2[i][j] = (f32x4){0.f, 0.f, 0.f, 0.f};
#pragma unroll
        for (int kc = 0; kc < 4; ++kc) {
#pragma unroll
            for (int kk = 0; kk < 2; ++kk) {
                bf16x8 a[2];
#pragma unroll
                for (int i = 0; i < 2; ++i)
                    a[i] = *(const bf16x8*)&Wvh[(size_t)(wid * 32 + i * 16 + r16) * 256 + kc * 64 + kk * 32 + kgrp * 8];
#pragma unroll
                for (int j = 0; j < 4; ++j) {
                    bf16x8 b = *(const bf16x8*)&Xs[(j * 16 + r16) * XS_LD + kc * 64 + kk * 32 + kgrp * 8];
#pragma unroll
                    for (int i = 0; i < 2; ++i)
                        acc2[i][j] = __builtin_amdgcn_mfma_f32_16x16x32_bf16(a[i], b, acc2[i][j], 0, 0, 0);
                }
            }
        }
#pragma unroll
        for (int i = 0; i < 2; ++i) {
#pragma unroll
            for (int j = 0; j < 4; ++j) {
                int n = j * 16 + r16;
#pragma unroll
                for (int r = 0; r < 4; ++r) {
                    int d = wid * 32 + i * 16 + kgrp * 4 + r;
                    VT[d * TL + n] = f2bf(acc2[i][j][r] + bv[h * 256 + d]);
                }
            }
        }
        __syncthreads();   // phi'd KT + VT visible
        // ---- ktv accumulate: C[m 32/wave][d 256] over n=64 ----
#pragma unroll
        for (int kk = 0; kk < 2; ++kk) {
            bf16x8 a[2];
#pragma unroll
            for (int i = 0; i < 2; ++i)
                a[i] = *(const bf16x8*)&KT[(wid * 32 + i * 16 + r16) * TL + kk * 32 + kgrp * 8];
#pragma unroll
            for (int j = 0; j < 16; ++j) {
                bf16x8 b = *(const bf16x8*)&VT[(j * 16 + r16) * TL + kk * 32 + kgrp * 8];
#pragma unroll
                for (int i = 0; i < 2; ++i)
                    kacc[i][j] = __builtin_amdgcn_mfma_f32_16x16x32_bf16(a[i], b, kacc[i][j], 0, 0, 0);
            }
        }
        __syncthreads();
    }
    // ---- epilogue: atomic accumulate ----
#pragma unroll
    for (int i = 0; i < 2; ++i) {
#pragma unroll
        for (int j = 0; j < 16; ++j) {
            int d = j * 16 + r16;
#pragma unroll
            for (int r = 0; r < 4; ++r) {
                int m = wid * 32 + i * 16 + kgrp * 4 + r;
                atomicAdd(&ktvT[(size_t)h * 65536 + (size_t)d * 256 + m], kacc[i][j][r]);
            }
        }
    }
    atomicAdd(&ksum[h * 256 + (t >> 1)], ksr);
}

// ---------------- pass 3: q proj + phi + num/den + vss(avg) + mean + time (512 thr, 80-row tiles) ----------------
__global__ __launch_bounds__(512, 2) void pass3_kernel(
    const float* __restrict__ qf, const u16* __restrict__ qb,
    const float* __restrict__ sf, const u16* __restrict__ sb, const int use_bf,
    const u16* __restrict__ Wqb, const float* __restrict__ bq,
    const float* __restrict__ ns_ptr, const u16* __restrict__ ktvb, const float* __restrict__ ksum,
    const u16* __restrict__ Wavg, const float* __restrict__ bavg, float* __restrict__ out)
{
    const int n0 = blockIdx.x * P3R;
    const int t = threadIdx.x;
    const int lane = t & 63, wid = t >> 6;      // 8 waves; wave = 80 rows x 32 cols
    const int r16 = lane & 15, kgrp = lane >> 4;
    const int C0 = wid * 32;

    __shared__ char smem[86016];
    u16* Xs = (u16*)smem;                        // [80][XS_LD] query tile  42240 B
    u16* Qs = (u16*)(smem + 42240);              // [80][XS_LD] phi_q (later source) 42240 B
    float* ksl = (float*)(smem + 84480);         // 256 f32
    float* den = (float*)(smem + 85504);         // 80 f32
    float* outs = (float*)smem;                  // epilogue alias (80*256 f32 = 81920 B)

    const float inv_ns = 1.0f / fabsf(ns_ptr[0]);

    // stage query tile (80 rows = 2560 int4)
#pragma unroll
    for (int p = 0; p < 5; ++p) {
        int id = p * 512 + t;
        int row = id >> 5, col = (id & 31) * 8;
        size_t gofs = (size_t)(n0 + row) * 256 + col;
        *(int4*)&Xs[row * XS_LD + col] = use_bf ? *(const int4*)&qb[gofs] : cvt8(qf + gofs);
    }
    __syncthreads();

    f32x4 oacc[5][2];
#pragma unroll
    for (int f = 0; f < 5; ++f)
#pragma unroll
        for (int j = 0; j < 2; ++j) oacc[f][j] = (f32x4){0.f, 0.f, 0.f, 0.f};

    for (int h = 0; h < NH; ++h) {
        if (t < 256) ksl[t] = ksum[h * 256 + t];
        // ---- q-GEMM: C[n 80][m 256], wave cols C0..C0+31 ----
        f32x4 acc[5][2];
#pragma unroll
        for (int f = 0; f < 5; ++f)
#pragma unroll
            for (int j = 0; j < 2; ++j) acc[f][j] = (f32x4){0.f, 0.f, 0.f, 0.f};
#pragma unroll
        for (int kc = 0; kc < 4; ++kc) {
#pragma unroll
            for (int kk = 0; kk < 2; ++kk) {
                bf16x8 a[5], b[2];
#pragma unroll
                for (int f = 0; f < 5; ++f)
                    a[f] = *(const bf16x8*)&Xs[(f * 16 + r16) * XS_LD + kc * 64 + kk * 32 + kgrp * 8];
#pragma unroll
                for (int j = 0; j < 2; ++j)
                    b[j] = *(const bf16x8*)&Wqb[(size_t)h * 65536 +
                        (size_t)(C0 + j * 16 + r16) * 256 + kc * 64 + kk * 32 + kgrp * 8];
#pragma unroll
                for (int f = 0; f < 5; ++f)
#pragma unroll
                    for (int j = 0; j < 2; ++j)
                        acc[f][j] = __builtin_amdgcn_mfma_f32_16x16x32_bf16(a[f], b[j], acc[f][j], 0, 0, 0);
            }
        }
        __syncthreads();   // prev head's num reads of Qs done
        // epilogue: (relu+eps)*inv_ns -> Qs
#pragma unroll
        for (int f = 0; f < 5; ++f) {
#pragma unroll
            for (int j = 0; j < 2; ++j) {
                int c = C0 + j * 16 + r16;
#pragma unroll
                for (int r = 0; r < 4; ++r) {
                    int n = f * 16 + kgrp * 4 + r;
                    float x = acc[f][j][r] + bq[h * 256 + c];
                    x = (fmaxf(x, 0.f) + FEPS) * inv_ns;
                    Qs[n * XS_LD + c] = f2bf(x);
                }
            }
        }
        __syncthreads();   // Qs + ksl visible
        // ---- phi row norms + apply + denominator (8 threads/row, 32 cols each) ----
#pragma unroll
        for (int rp = 0; rp < 2; ++rp) {
            int row = rp * 64 + (t >> 3);
            if (row < P3R) {
                int q = t & 7;
                float s1 = 0.f, s2 = 0.f;
                bf16x8 v8s[4];
#pragma unroll
                for (int j = 0; j < 4; ++j) {
                    v8s[j] = *(const bf16x8*)&Qs[row * XS_LD + q * 32 + j * 8];
#pragma unroll
                    for (int jj = 0; jj < 8; ++jj) {
                        float x = bf2f((u16)v8s[j][jj]);
                        float qq = x * x;
                        s1 += qq; s2 += qq * qq;
                    }
                }
                s1 += __shfl_xor(s1, 1, 64); s1 += __shfl_xor(s1, 2, 64); s1 += __shfl_xor(s1, 4, 64);
                s2 += __shfl_xor(s2, 1, 64); s2 += __shfl_xor(s2, 2, 64); s2 += __shfl_xor(s2, 4, 64);
                float sc = sqrtf(s1) / sqrtf(s2);
                float dp = 0.f;
#pragma unroll
                for (int j = 0; j < 4; ++j) {
                    bf16x8 w8;
#pragma unroll
                    for (int jj = 0; jj < 8; ++jj) {
                        float x = bf2f((u16)v8s[j][jj]);
                        float ph = x * x * sc;
                        u16 pb = f2bf(ph);
                        w8[jj] = (short)pb;
                        dp += bf2f(pb) * ksl[q * 32 + j * 8 + jj];
                    }
                    *(bf16x8*)&Qs[row * XS_LD + q * 32 + j * 8] = w8;
                }
                dp += __shfl_xor(dp, 1, 64); dp += __shfl_xor(dp, 2, 64); dp += __shfl_xor(dp, 4, 64);
                if (q == 0) den[row] = 0.125f / (dp + FEPS);   // mean-over-heads folded
            }
        }
        __syncthreads();   // phi'd Qs + den visible
        // ---- numerator GEMM: C[n][o] = phi_q x ktv[h] ----
#pragma unroll
        for (int f = 0; f < 5; ++f)
#pragma unroll
            for (int j = 0; j < 2; ++j) acc[f][j] = (f32x4){0.f, 0.f, 0.f, 0.f};
#pragma unroll
        for (int kc = 0; kc < 4; ++kc) {
#pragma unroll
            for (int kk = 0; kk < 2; ++kk) {
                bf16x8 a[5], b[2];
#pragma unroll
                for (int f = 0; f < 5; ++f)
                    a[f] = *(const bf16x8*)&Qs[(f * 16 + r16) * XS_LD + kc * 64 + kk * 32 + kgrp * 8];
#pragma unroll
                for (int j = 0; j < 2; ++j)
                    b[j] = *(const bf16x8*)&ktvb[(size_t)h * 65536 +
                        (size_t)(C0 + j * 16 + r16) * 256 + kc * 64 + kk * 32 + kgrp * 8];
#pragma unroll
                for (int f = 0; f < 5; ++f)
#pragma unroll
                    for (int j = 0; j < 2; ++j)
                        acc[f][j] = __builtin_amdgcn_mfma_f32_16x16x32_bf16(a[f], b[j], acc[f][j], 0, 0, 0);
            }
        }
#pragma unroll
        for (int f = 0; f < 5; ++f) {
#pragma unroll
            for (int r = 0; r < 4; ++r) {
                float dr = den[f * 16 + kgrp * 4 + r];
#pragma unroll
                for (int j = 0; j < 2; ++j)
                    oacc[f][j][r] += acc[f][j][r] * dr;
            }
        }
    }
    __syncthreads();       // all num-GEMM Qs reads done
    // ---- stage source tile into Qs region ----
#pragma unroll
    for (int p = 0; p < 5; ++p) {
        int id = p * 512 + t;
        int row = id >> 5, col = (id & 31) * 8;
        size_t gofs = (size_t)(n0 + row) * 256 + col;
        *(int4*)&Qs[row * XS_LD + col] = use_bf ? *(const int4*)&sb[gofs] : cvt8(sf + gofs);
    }
    __syncthreads();
    // ---- vss GEMM: C[n][o] = src x Wavg^T ----
    f32x4 vacc[5][2];
#pragma unroll
    for (int f = 0; f < 5; ++f)
#pragma unroll
        for (int j = 0; j < 2; ++j) vacc[f][j] = (f32x4){0.f, 0.f, 0.f, 0.f};
#pragma unroll
    for (int kc = 0; kc < 4; ++kc) {
#pragma unroll
        for (int kk = 0; kk < 2; ++kk) {
            bf16x8 a[5], b[2];
#pragma unroll
            for (int f = 0; f < 5; ++f)
                a[f] = *(const bf16x8*)&Qs[(f * 16 + r16) * XS_LD + kc * 64 + kk * 32 + kgrp * 8];
#pragma unroll
            for (int j = 0; j < 2; ++j)
                b[j] = *(const bf16x8*)&Wavg[(size_t)(C0 + j * 16 + r16) * 256 + kc * 64 + kk * 32 + kgrp * 8];
#pragma unroll
            for (int f = 0; f < 5; ++f)
#pragma unroll
                for (int j = 0; j < 2; ++j)
                    vacc[f][j] = __builtin_amdgcn_mfma_f32_16x16x32_bf16(a[f], b[j], vacc[f][j], 0, 0, 0);
        }
    }
    __syncthreads();   // Xs/Qs reads done before outs alias writes
    // ---- combine into LDS ----
#pragma unroll
    for (int f = 0; f < 5; ++f) {
#pragma unroll
        for (int j = 0; j < 2; ++j) {
            int c = C0 + j * 16 + r16;
            float bo = bavg[c];
#pragma unroll
            for (int r = 0; r < 4; ++r) {
                int n = f * 16 + kgrp * 4 + r;
                outs[n * 256 + c] = oacc[f][j][r] + vacc[f][j][r] + bo;
            }
        }
    }
    __syncthreads();
    // ---- time component ----
#pragma unroll
    for (int rp = 0; rp < 2; ++rp) {
        int row = rp * 64 + (t >> 3);
        if (row < P3R) {
            int q = t & 7;
            float s = 0.f;
#pragma unroll
            for (int c4 = 0; c4 < 8; ++c4) {
                float4 v = *(const float4*)&outs[row * 256 + q * 32 + c4 * 4];
                s += v.x * v.x + v.y * v.y + v.z * v.z + v.w * v.w;
            }
            s += __shfl_xor(s, 1, 64); s += __shfl_xor(s, 2, 64); s += __shfl_xor(s, 4, 64);
            if (q == 0)
                out[(size_t)(n0 + row) * 257] = sqrtf(s + 1.0f);
        }
    }
    // ---- space components ----
    {
        int col = t & 255, half = t >> 8;
        for (int rr = 0; rr < 40; ++rr) {
            int row = half * 40 + rr;
            out[(size_t)(n0 + row) * 257 + 1 + col] = outs[row * 256 + col];
        }
    }
}

extern "C" void kernel_launch(void* const* d_in, const int* in_sizes, int n_in,
                              void* d_out, int out_size, void* d_ws, size_t ws_size,
                              hipStream_t stream)
{
    const float* query  = (const float*)d_in[0];
    const float* source = (const float*)d_in[1];
    const float* Wq_w   = (const float*)d_in[2];
    const float* Wq_b   = (const float*)d_in[3];
    const float* Wk_w   = (const float*)d_in[4];
    const float* Wk_b   = (const float*)d_in[5];
    const float* Wv_w   = (const float*)d_in[6];
    const float* Wv_b   = (const float*)d_in[7];
    const float* ns     = (const float*)d_in[8];
    const float* vmap_w = (const float*)d_in[9];
    const float* vmap_b = (const float*)d_in[10];
    float* out = (float*)d_out;

    char* ws = (char*)d_ws;
    size_t off = 0;
    auto alloc = [&](size_t bytes) -> char* {
        char* p = ws + off;
        off += (bytes + 255) & ~(size_t)255;
        return p;
    };
    float* ktvT = (float*)alloc((size_t)NH * 65536 * 4);   // [h][d][m] fp32 accum
    float* ksum = (float*)alloc((size_t)NH * 256 * 4);     // adjacent for one memset
    u16*   Wqb  = (u16*)alloc((size_t)NH * 65536 * 2);
    u16*   Wkb  = (u16*)alloc((size_t)NH * 65536 * 2);
    u16*   Wvb  = (u16*)alloc((size_t)NH * 65536 * 2);
    u16*   Wavg = (u16*)alloc((size_t)65536 * 2);
    float* bavg = (float*)alloc((size_t)256 * 4);
    u16*   ktvb = (u16*)alloc((size_t)NH * 65536 * 2);
    size_t base_need = off;

    // optional bf16 source/query copies
    u16* qbf = (u16*)alloc((size_t)N_NODES * 256 * 2);
    u16* sbf = (u16*)alloc((size_t)N_NODES * 256 * 2);
    int use_bf = (off <= ws_size) ? 1 : 0;

    if (base_need > ws_size) {
        hipMemsetAsync(d_out, 0x7f, (size_t)out_size * 4, stream);
        return;
    }

    hipMemsetAsync(ktvT, 0, (size_t)NH * 65536 * 4 + (size_t)NH * 256 * 4, stream);

    f2bf4_kernel<<<512, 256, 0, stream>>>(Wq_w, Wqb, NH * 65536 / 4);
    f2bf4_kernel<<<512, 256, 0, stream>>>(Wk_w, Wkb, NH * 65536 / 4);
    f2bf4_kernel<<<512, 256, 0, stream>>>(Wv_w, Wvb, NH * 65536 / 4);
    if (use_bf) {
        f2bf4_kernel<<<5000, 256, 0, stream>>>(query, qbf, N_NODES * 256 / 4);
        f2bf4_kernel<<<5000, 256, 0, stream>>>(source, sbf, N_NODES * 256 / 4);
    }
    wavg_kernel<<<256, 256, 0, stream>>>(Wv_w, vmap_w, Wavg);
    bavg_kernel<<<1, 256, 0, stream>>>(vmap_w, Wv_b, vmap_b, bavg);

    pass2_kernel<<<256, 512, 0, stream>>>(source, sbf, use_bf, Wkb, Wk_b, Wvb, Wv_b, ns, ktvT, ksum);
    f2bf4_kernel<<<512, 256, 0, stream>>>(ktvT, ktvb, NH * 65536 / 4);
    pass3_kernel<<<250, 512, 0, stream>>>(query, qbf, source, sbf, use_bf,
                                          Wqb, Wq_b, ns, ktvb, ksum, Wavg, bavg, out);
}